// Round 10
// baseline (272.604 us; speedup 1.0000x reference)
//
#include <hip/hip_runtime.h>
#include <hip/hip_bf16.h>

#define SEQ 2048
#define HID 1024
#define NH 16
#define HD 64
#define QKVLD 3072

typedef __attribute__((ext_vector_type(8))) short bf16x8;
typedef __attribute__((ext_vector_type(4))) float f32x4;
typedef unsigned short us;

__device__ __forceinline__ us f2bf(float f) {
  unsigned int x = __float_as_uint(f);
  x += 0x7fffu + ((x >> 16) & 1u);
  return (us)(x >> 16);
}

// packed f32x2 -> bf16x2 (v_cvt_pk_bf16_f32, RNE)
__device__ __forceinline__ unsigned int pkbf(float a, float b) {
  union { __hip_bfloat162 h2; unsigned int u; } cvt;
  cvt.h2 = __float22bfloat162_rn(make_float2(a, b));
  return cvt.u;
}

__device__ __forceinline__ void gld_lds16(const void* g, void* l) {
  __builtin_amdgcn_global_load_lds((__attribute__((address_space(1))) void*)g,
                                   (__attribute__((address_space(3))) void*)l, 16, 0, 0);
}

__device__ __forceinline__ f32x4 mfma(bf16x8 a, bf16x8 b, f32x4 c) {
  return __builtin_amdgcn_mfma_f32_16x16x32_bf16(a, b, c, 0, 0, 0);
}

#define NBLK 512

// software grid barrier: all NBLK blocks are co-resident by construction
// (launch_bounds(256,2), 28 KB LDS -> 2 blocks/CU x 256 CUs = 512).
// Release/acquire via device-scope atomics (cross-XCD coherent, m20).
// Each slot is single-use per kernel invocation (init kernel zeroes them).
__device__ __forceinline__ void gridbar(unsigned int* bar, int idx) {
  __syncthreads();
  if (threadIdx.x == 0) {
    __threadfence();  // release: prior global writes visible device-wide
    unsigned int prev = atomicAdd(&bar[idx * 2], 1u);
    if (prev == NBLK - 1) {
      atomicExch(&bar[idx * 2 + 1], 1u);
    } else {
      while (atomicAdd(&bar[idx * 2 + 1], 0u) == 0u)
        __builtin_amdgcn_s_sleep(8);
    }
    __threadfence();  // acquire
  }
  __syncthreads();
}

__global__ void bar_init(unsigned int* bar) {
  if (threadIdx.x < 8) bar[threadIdx.x] = 0u;
}

// ---------------- single fused persistent kernel ----------------
// grid 512 x 256, 2 blocks/CU co-resident. Static LDS 28672 B.
// Phase 0: X f32->bf16 + 4 weight transposes (Wq scaled 0.125 = 1/sqrt(HD)).
// Phase 1: QKV GEMM 128x96 BK=64, XCD-rect swizzle, V written transposed.
// Phase 2: sparse flash attention (S^T form, fixed-max softmax, single-buf K/V).
// Phase 3: out-proj GEMM 64x64 BK=64, XCD-rect swizzle, f32 out.
__global__ __launch_bounds__(256, 2) void fused(
    const float* __restrict__ X, const float* __restrict__ Wq,
    const float* __restrict__ Wk, const float* __restrict__ Wv,
    const float* __restrict__ Wo, float* __restrict__ out,
    us* __restrict__ Xb, us* __restrict__ WtQKV, us* __restrict__ WtO,
    us* __restrict__ QKV, us* __restrict__ VtG, us* __restrict__ AttO,
    unsigned int* bar) {
  __shared__ __align__(16) unsigned char smem[28672];
  const int lin = blockIdx.x;
  const int tid = threadIdx.x;
  const int lane = tid & 63, w = tid >> 6;
  const int quad = lane >> 4, l16 = lane & 15;

  // ================= phase 0: prep =================
  {
    size_t base = (size_t)lin * 4096 + tid * 4;
#pragma unroll
    for (int i = 0; i < 4; i++) {
      float4 v = *(const float4*)(X + base + i * 1024);
      *(uint2*)(Xb + base + i * 1024) = make_uint2(pkbf(v.x, v.y), pkbf(v.z, v.w));
    }
    float* tile = (float*)smem;  // [32][33]
    const int tx = tid & 31, ty = tid >> 5;
    for (int tt = lin; tt < 4096; tt += 512) {
      const int z = tt >> 10, rem = tt & 1023;
      const int r0 = (rem >> 5) * 32, c0 = (rem & 31) * 32;
      const float* S = (z == 0) ? Wq : (z == 1) ? Wk : (z == 2) ? Wv : Wo;
      us* D = (z < 3) ? (WtQKV + (size_t)z * HID * HID) : WtO;
      const float scale = (z == 0) ? 0.125f : 1.0f;
#pragma unroll
      for (int k = 0; k < 4; k++)
        tile[(ty + k * 8) * 33 + tx] = S[(size_t)(r0 + ty + k * 8) * HID + c0 + tx];
      __syncthreads();
#pragma unroll
      for (int k = 0; k < 4; k++)
        D[(size_t)(c0 + ty + k * 8) * HID + r0 + tx] = f2bf(scale * tile[tx * 33 + ty + k * 8]);
      __syncthreads();
    }
  }
  gridbar(bar, 0);

  // ================= phase 1: QKV GEMM (128x96, BK=64) =================
  {
    us* As = (us*)smem;       // 128*64 = 16384 B
    us* Bs = As + 128 * 64;   // 96*64  = 12288 B (total 28672)
    const int wm = w >> 1, wn = w & 1;
    const int xcd = lin & 7, idx = lin >> 3;
    const int bx = (xcd & 3) * 8 + (idx & 7);
    const int by = (xcd >> 2) * 8 + (idx >> 3);
    const int bm = by * 128, bn = bx * 96;

    f32x4 acc[4][3] = {};

    for (int k0 = 0; k0 < HID; k0 += 64) {
#pragma unroll
      for (int c = tid; c < 1024; c += 256) {
        int r = c >> 3, kc = c & 7;
        int g = (kc & 4) + ((kc & 3) ^ (r & 3));
        gld_lds16(Xb + (size_t)(bm + r) * HID + k0 + g * 8, As + c * 8);
      }
#pragma unroll
      for (int c = tid; c < 768; c += 256) {
        int r = c >> 3, kc = c & 7;
        int g = (kc & 4) + ((kc & 3) ^ (r & 3));
        gld_lds16(WtQKV + (size_t)(bn + r) * HID + k0 + g * 8, Bs + c * 8);
      }
      __syncthreads();
      bf16x8 af[2][4], bfr[2][3];
#pragma unroll
      for (int ks = 0; ks < 2; ks++) {
#pragma unroll
        for (int mi = 0; mi < 4; mi++) {
          int m = wm * 64 + mi * 16 + l16;
          af[ks][mi] = *(const bf16x8*)(As + (m * 8 + ks * 4 + (quad ^ (m & 3))) * 8);
        }
#pragma unroll
        for (int ni = 0; ni < 3; ni++) {
          int n = wn * 48 + ni * 16 + l16;
          bfr[ks][ni] = *(const bf16x8*)(Bs + (n * 8 + ks * 4 + (quad ^ (n & 3))) * 8);
        }
      }
#pragma unroll
      for (int mi = 0; mi < 4; mi++)
#pragma unroll
        for (int ni = 0; ni < 3; ni++) {
          acc[mi][ni] = mfma(af[0][mi], bfr[0][ni], acc[mi][ni]);
          acc[mi][ni] = mfma(af[1][mi], bfr[1][ni], acc[mi][ni]);
        }
      __syncthreads();
    }

#pragma unroll
    for (int mi = 0; mi < 4; mi++) {
#pragma unroll
      for (int ni = 0; ni < 3; ni++) {
        int row = bm + wm * 64 + mi * 16 + quad * 4;
        int col = bn + wn * 48 + ni * 16 + l16;
        if (col < 2 * HID) {
#pragma unroll
          for (int r = 0; r < 4; r++)
            QKV[(size_t)(row + r) * QKVLD + col] = f2bf(acc[mi][ni][r]);
        } else {
          *(uint2*)(VtG + (size_t)(col - 2 * HID) * SEQ + row) =
              make_uint2(pkbf(acc[mi][ni][0], acc[mi][ni][1]),
                         pkbf(acc[mi][ni][2], acc[mi][ni][3]));
        }
      }
    }
  }
  gridbar(bar, 1);

  // ================= phase 2: sparse flash attention (single-buf) =================
  {
    us* Ks = (us*)smem;        // 64*64 = 8192 B
    us* Vt = Ks + 4096;        // 64*64 = 8192 B
    us* Pw = Vt + 4096;        // 4 x 16*72 = 9216 B (total 25600)
    const int xcd = lin & 7, slot = lin >> 3;
    const int h = slot >> 2;
    const int qbase = (xcd * 4 + (slot & 3)) * 64;
    const int qrow0 = qbase + w * 16;
    us* pws = Pw + w * (16 * 72);

    bf16x8 aq[2];
    {
      const us* qp = QKV + (size_t)(qrow0 + l16) * QKVLD + h * HD + quad * 8;
      aq[0] = *(const bf16x8*)qp;
      aq[1] = *(const bf16x8*)(qp + 32);
    }

    f32x4 accO[4] = {};
    float lsum = 0.f;

    const int jlo = (qbase >= 512) ? (qbase - 512) : 0;
    const int ng = (jlo > 0) ? ((jlo + 511) >> 9) : 0;
    const int ntl = ((qbase - jlo) >> 6) + 1;

    for (int t = 0; t < ntl; t++) {
      const int j0 = jlo + t * 64;
      if (t > 0) __syncthreads();
#pragma unroll
      for (int c = tid; c < 512; c += 256) {
        int r = c >> 3, kc = c & 7;
        int g = (kc & 4) + ((kc & 3) ^ (r & 3));
        gld_lds16(QKV + (size_t)(j0 + r) * QKVLD + HID + h * HD + g * 8, Ks + c * 8);
        gld_lds16(VtG + (size_t)(h * HD + r) * SEQ + j0 + g * 8, Vt + c * 8);
      }
      __syncthreads();

      f32x4 s[4] = {};
#pragma unroll
      for (int nj = 0; nj < 4; nj++) {
        int row = nj * 16 + l16;
#pragma unroll
        for (int ks = 0; ks < 2; ks++) {
          bf16x8 ak = *(const bf16x8*)(Ks + (row * 8 + ks * 4 + (quad ^ (row & 3))) * 8);
          s[nj] = mfma(ak, aq[ks], s[nj]);
        }
      }

      const bool isdiag = (t == ntl - 1);
      const bool istrail = (t == 0) && (qbase >= 512);
      const int trailg = (istrail && ((j0 & 511) == 0)) ? 1 : 0;
      const int db = qrow0 + l16 - j0 - quad * 4;  // i-j = db - nj*16 - r
#pragma unroll
      for (int nj = 0; nj < 4; nj++) {
        float p[4];
#pragma unroll
        for (int r = 0; r < 4; r++) {
          float x = s[nj][r];
          int d = db - nj * 16 - r;
          bool valid = true;
          if (isdiag) valid = (d >= 0);
          else if (istrail) valid = (d <= 512) || (trailg && (nj * 16 + quad * 4 + r) == 0);
          x = valid ? x : -1e30f;
          p[r] = __expf(x);
          lsum += p[r];
        }
        *(uint2*)(pws + l16 * 72 + nj * 16 + quad * 4) =
            make_uint2(pkbf(p[0], p[1]), pkbf(p[2], p[3]));
      }

#pragma unroll
      for (int kk = 0; kk < 2; kk++) {
        bf16x8 bp = *(const bf16x8*)(pws + l16 * 72 + kk * 32 + quad * 8);
#pragma unroll
        for (int nd = 0; nd < 4; nd++) {
          int row = nd * 16 + l16;
          bf16x8 av = *(const bf16x8*)(Vt + (row * 8 + kk * 4 + (quad ^ (row & 3))) * 8);
          accO[nd] = mfma(av, bp, accO[nd]);
        }
      }
    }

    if (ng > 0) {
      __syncthreads();
      if (tid < ng * 8) {  // K rows c<ng at j=512c
        int r = tid >> 3, kc = tid & 7;
        int g = (kc & 4) + ((kc & 3) ^ (r & 3));
        *(uint4*)(Ks + tid * 8) =
            *(const uint4*)(QKV + ((size_t)r << 9) * QKVLD + HID + h * HD + g * 8);
      }
      if (tid < ng * 64) {  // V^T cols c<ng
        int d = tid & 63, c = tid >> 6;
        Vt[(d * 8 + (d & 3)) * 8 + c] = VtG[(size_t)(h * HD + d) * SEQ + ((size_t)c << 9)];
      }
      __syncthreads();
      f32x4 s0 = {};
#pragma unroll
      for (int ks = 0; ks < 2; ks++) {
        bf16x8 ak = *(const bf16x8*)(Ks + (l16 * 8 + ks * 4 + (quad ^ (l16 & 3))) * 8);
        s0 = mfma(ak, aq[ks], s0);
      }
      float p[4];
#pragma unroll
      for (int r = 0; r < 4; r++) {
        p[r] = ((quad * 4 + r) < ng) ? __expf(s0[r]) : 0.f;
        lsum += p[r];
      }
      *(uint2*)(pws + l16 * 72 + quad * 4) = make_uint2(pkbf(p[0], p[1]), pkbf(p[2], p[3]));
      *(uint2*)(pws + l16 * 72 + 16 + quad * 4) = make_uint2(0, 0);
      bf16x8 bp = *(const bf16x8*)(pws + l16 * 72 + quad * 8);
#pragma unroll
      for (int nd = 0; nd < 4; nd++) {
        int row = nd * 16 + l16;
        bf16x8 av = *(const bf16x8*)(Vt + (row * 8 + (quad ^ (row & 3))) * 8);
        accO[nd] = mfma(av, bp, accO[nd]);
      }
    }

    lsum += __shfl_xor(lsum, 16);
    lsum += __shfl_xor(lsum, 32);
    const float rl = 1.0f / lsum;
    const int i = qrow0 + l16;
#pragma unroll
    for (int nd = 0; nd < 4; nd++) {
      *(uint2*)(AttO + (size_t)i * HID + h * HD + nd * 16 + quad * 4) =
          make_uint2(pkbf(accO[nd][0] * rl, accO[nd][1] * rl),
                     pkbf(accO[nd][2] * rl, accO[nd][3] * rl));
    }
  }
  gridbar(bar, 2);

  // ================= phase 3: out-proj GEMM (64x64, BK=64) =================
  {
    us* As = (us*)smem;       // 64*64 = 8192 B
    us* Bs = As + 64 * 64;    // 64*64 = 8192 B (total 16384)
    const int wm = w >> 1, wn = w & 1;
    const int xcd = lin & 7, idx = lin >> 3;
    const int bx = (xcd & 3) * 4 + (idx & 3);
    const int by = (xcd >> 2) * 16 + (idx >> 2);
    const int bm = by * 64, bn = bx * 64;

    f32x4 acc[2][2] = {};

    for (int k0 = 0; k0 < HID; k0 += 64) {
#pragma unroll
      for (int c = tid; c < 512; c += 256) {
        int r = c >> 3, kc = c & 7;
        int g = (kc & 4) + ((kc & 3) ^ (r & 3));
        gld_lds16(AttO + (size_t)(bm + r) * HID + k0 + g * 8, As + c * 8);
        gld_lds16(WtO + (size_t)(bn + r) * HID + k0 + g * 8, Bs + c * 8);
      }
      __syncthreads();
#pragma unroll
      for (int ks = 0; ks < 2; ks++) {
        bf16x8 af[2], bfr[2];
#pragma unroll
        for (int mi = 0; mi < 2; mi++) {
          int m = wm * 32 + mi * 16 + l16;
          af[mi] = *(const bf16x8*)(As + (m * 8 + ks * 4 + (quad ^ (m & 3))) * 8);
        }
#pragma unroll
        for (int ni = 0; ni < 2; ni++) {
          int n = wn * 32 + ni * 16 + l16;
          bfr[ni] = *(const bf16x8*)(Bs + (n * 8 + ks * 4 + (quad ^ (n & 3))) * 8);
        }
#pragma unroll
        for (int mi = 0; mi < 2; mi++)
#pragma unroll
          for (int ni = 0; ni < 2; ni++)
            acc[mi][ni] = mfma(af[mi], bfr[ni], acc[mi][ni]);
      }
      __syncthreads();
    }

#pragma unroll
    for (int mi = 0; mi < 2; mi++)
#pragma unroll
      for (int ni = 0; ni < 2; ni++) {
        int row = bm + wm * 32 + mi * 16 + quad * 4;
        int col = bn + wn * 32 + ni * 16 + l16;
#pragma unroll
        for (int r = 0; r < 4; r++)
          out[(size_t)(row + r) * HID + col] = acc[mi][ni][r];
      }
  }
}

extern "C" void kernel_launch(void* const* d_in, const int* in_sizes, int n_in,
                              void* d_out, int out_size, void* d_ws, size_t ws_size,
                              hipStream_t stream) {
  const float* X  = (const float*)d_in[0];
  const float* Wq = (const float*)d_in[1];
  const float* Wk = (const float*)d_in[2];
  const float* Wv = (const float*)d_in[3];
  const float* Wo = (const float*)d_in[4];
  float* out = (float*)d_out;

  us* Xb    = (us*)d_ws;                         // 2048x1024
  us* WtQKV = Xb + (size_t)SEQ * HID;            // 3072x1024
  us* WtO   = WtQKV + (size_t)QKVLD * HID;       // 1024x1024
  us* QKV   = WtO + (size_t)HID * HID;           // 2048x3072 (V block unused)
  us* VtG   = QKV + (size_t)SEQ * QKVLD;         // 1024x2048 (V transposed)
  us* AttO  = VtG + (size_t)HID * SEQ;           // 2048x1024
  unsigned int* bar = (unsigned int*)((char*)d_ws + (64u << 20));  // 64 MB offset, clear of arrays

  bar_init<<<dim3(1), dim3(64), 0, stream>>>(bar);
  fused<<<dim3(NBLK), dim3(256), 0, stream>>>(X, Wq, Wk, Wv, Wo, out,
                                              Xb, WtQKV, WtO, QKV, VtG, AttO, bar);
}

// Round 11
// 127.784 us; speedup vs baseline: 2.1333x; 2.1333x over previous
//
#include <hip/hip_runtime.h>
#include <hip/hip_bf16.h>

#define SEQ 2048
#define HID 1024
#define NH 16
#define HD 64
#define QKVLD 3072

typedef __attribute__((ext_vector_type(8))) short bf16x8;
typedef __attribute__((ext_vector_type(4))) float f32x4;

__device__ __forceinline__ unsigned short f2bf(float f) {
  unsigned int x = __float_as_uint(f);
  x += 0x7fffu + ((x >> 16) & 1u);
  return (unsigned short)(x >> 16);
}

// packed f32x2 -> bf16x2 (v_cvt_pk_bf16_f32, RNE - same rounding as f2bf)
__device__ __forceinline__ unsigned int pkbf(float a, float b) {
  union { __hip_bfloat162 h2; unsigned int u; } cvt;
  cvt.h2 = __float22bfloat162_rn(make_float2(a, b));
  return cvt.u;
}

__device__ __forceinline__ void gld_lds16(const void* g, void* l) {
  __builtin_amdgcn_global_load_lds((__attribute__((address_space(1))) void*)g,
                                   (__attribute__((address_space(3))) void*)l, 16, 0, 0);
}

// ---------------- prep: z<4 -> weight transpose f32->bf16^T, z==4 -> cvt X ----------------
// z=0: Wq (scaled by 0.125 = 1/sqrt(HD)), z=1: Wk, z=2: Wv, z=3: Wo
__global__ void prep(const float* __restrict__ X, const float* __restrict__ Wq,
                     const float* __restrict__ Wk, const float* __restrict__ Wv,
                     const float* __restrict__ Wo, unsigned short* __restrict__ Xb,
                     unsigned short* __restrict__ WtQKV, unsigned short* __restrict__ WtO) {
  const int z = blockIdx.z;
  if (z == 4) {  // convert X -> bf16, 1024 blocks x 2048 elems
    int bid = blockIdx.y * 32 + blockIdx.x;
    int t = threadIdx.y * 32 + threadIdx.x;
    size_t base = (size_t)bid * 2048 + t * 4;
#pragma unroll
    for (int half = 0; half < 2; half++) {
      float4 v = *(const float4*)(X + base + half * 1024);
      *(uint2*)(Xb + base + half * 1024) = make_uint2(pkbf(v.x, v.y), pkbf(v.z, v.w));
    }
    return;
  }
  __shared__ float tile[32][33];
  const float* S = (z == 0) ? Wq : (z == 1) ? Wk : (z == 2) ? Wv : Wo;
  unsigned short* D = (z < 3) ? (WtQKV + (size_t)z * HID * HID) : WtO;
  const float scale = (z == 0) ? 0.125f : 1.0f;
  int r0 = blockIdx.y * 32, c0 = blockIdx.x * 32;
  int tx = threadIdx.x, ty = threadIdx.y;
#pragma unroll
  for (int k = 0; k < 4; k++)
    tile[ty + k * 8][tx] = S[(size_t)(r0 + ty + k * 8) * HID + c0 + tx];
  __syncthreads();
#pragma unroll
  for (int k = 0; k < 4; k++)
    D[(size_t)(c0 + ty + k * 8) * HID + r0 + tx] = f2bf(scale * tile[tx][ty + k * 8]);
}

// ---------------- GEMM: C[M,N] = A[M,K](bf16) * Bt[N,K](bf16)^T ----------------
// Tile (MI*32) x BN, BK=128. 4 waves in 2x2; wave tile (MI*16) x (BN/2).
// LDS row: 16 chunks of 16B; slot kc holds global chunk g=(kc&12)+((kc&3)^(r&3))
// (XOR swizzle per 32-k half). Frag read for (ks,quad): chunk ks*4+(quad^(r&3)).
// XCD-rect block swizzle: lin&7 = XCD (dispatch heuristic); each XCD gets a
// contiguous rectangle of 64 blocks so its A/B slices fit the 4 MB per-XCD L2.
// OUT==0: f32 row-major. OUT==2: bf16 row-major for cols<2048, transposed
// ushort4 into Vout for cols>=2048 (the V block of the QKV projection).
template <int MI, int BN, int GX, int RW, int OUT>
__global__ __launch_bounds__(256, 2) void gemm_bt(const unsigned short* __restrict__ A,
                                                  const unsigned short* __restrict__ Bt,
                                                  void* __restrict__ Cout,
                                                  unsigned short* __restrict__ Vout,
                                                  int M, int N, int K) {
  constexpr int NI = BN / 32;   // per-wave n-frags (wave covers BN/2 cols)
  constexpr int TM = MI * 32;   // block rows
  __shared__ unsigned short As[TM * 128];
  __shared__ unsigned short Bs[BN * 128];
  const int tid = threadIdx.x;
  const int lane = tid & 63;
  const int w = tid >> 6;
  const int wm = w >> 1, wn = w & 1;
  const int quad = lane >> 4, l16 = lane & 15;

  const int lin = blockIdx.x + GX * blockIdx.y;
  const int xcd = lin & 7, idx = lin >> 3;
  const int bx = (xcd & 3) * RW + (idx % RW);
  const int by = (xcd >> 2) * (64 / RW) + (idx / RW);
  const int bm = by * TM, bn = bx * BN;

  f32x4 acc[MI][NI] = {};

  for (int k0 = 0; k0 < K; k0 += 128) {
#pragma unroll
    for (int c = tid; c < TM * 16; c += 256) {
      int r = c >> 4, kc = c & 15;
      int g = (kc & 12) + ((kc & 3) ^ (r & 3));
      gld_lds16(A + (size_t)(bm + r) * K + k0 + g * 8, As + c * 8);
    }
#pragma unroll
    for (int c = tid; c < BN * 16; c += 256) {
      int r = c >> 4, kc = c & 15;
      int g = (kc & 12) + ((kc & 3) ^ (r & 3));
      gld_lds16(Bt + (size_t)(bn + r) * K + k0 + g * 8, Bs + c * 8);
    }
    __syncthreads();
#pragma unroll
    for (int ks = 0; ks < 4; ks++) {
      bf16x8 af[MI], bfr[NI];
#pragma unroll
      for (int mi = 0; mi < MI; mi++) {
        int m = wm * (MI * 16) + mi * 16 + l16;
        af[mi] = *(const bf16x8*)(As + (m * 16 + ks * 4 + (quad ^ (m & 3))) * 8);
      }
#pragma unroll
      for (int ni = 0; ni < NI; ni++) {
        int n = wn * (BN / 2) + ni * 16 + l16;
        bfr[ni] = *(const bf16x8*)(Bs + (n * 16 + ks * 4 + (quad ^ (n & 3))) * 8);
      }
#pragma unroll
      for (int mi = 0; mi < MI; mi++)
#pragma unroll
        for (int ni = 0; ni < NI; ni++)
          acc[mi][ni] = __builtin_amdgcn_mfma_f32_16x16x32_bf16(af[mi], bfr[ni], acc[mi][ni], 0, 0, 0);
    }
    __syncthreads();
  }

#pragma unroll
  for (int mi = 0; mi < MI; mi++) {
#pragma unroll
    for (int ni = 0; ni < NI; ni++) {
      int row = bm + wm * (MI * 16) + mi * 16 + quad * 4;
      int col = bn + wn * (BN / 2) + ni * 16 + l16;
      if (OUT == 0) {
#pragma unroll
        for (int r = 0; r < 4; r++)
          ((float*)Cout)[(size_t)(row + r) * N + col] = acc[mi][ni][r];
      } else {
        if (col < 2 * HID) {
#pragma unroll
          for (int r = 0; r < 4; r++)
            ((unsigned short*)Cout)[(size_t)(row + r) * N + col] = f2bf(acc[mi][ni][r]);
        } else {
          *(uint2*)(Vout + (size_t)(col - 2 * HID) * SEQ + row) =
              make_uint2(pkbf(acc[mi][ni][0], acc[mi][ni][1]),
                         pkbf(acc[mi][ni][2], acc[mi][ni][3]));
        }
      }
    }
  }
}

// ---------------- sparse flash attention (S^T form, fixed-max softmax) ----------------
// grid (SEQ/64, NH) linearized; XCD-aware remap: lin%8 selects the XCD so each
// XCD gets contiguous q-block runs whose K/V slices stay L2-resident.
// Double-buffered K/V tiles: staging for tile t+1 issues before computing tile
// t; ONE barrier per tile (buffer B=(t+1)&1 was last read at t-1, whose barrier
// fences it) -> vmcnt drain overlaps a full tile of compute. LDS 41 KB, 3/CU.
// Wave w handles q rows [qbase+w*16,+16). S^T = K·Q^T so C-layout row=j, col=i:
// lsum per-lane f32 scalar, P^T packs via v_cvt_pk_bf16_f32, O^T -> uint2 store.
// Q pre-scaled by 1/sqrt(HD); no exp clamp (scores ~N(0,1), max ~5.5 sigma).
__global__ __launch_bounds__(256, 3) void attn_sparse(const unsigned short* __restrict__ QKV,
                                                      const unsigned short* __restrict__ VtG,
                                                      unsigned short* __restrict__ AttO) {
  __shared__ unsigned short Ks[2][64 * 64];  // K tile [j][d], swizzled chunks
  __shared__ unsigned short Vt[2][64 * 64];  // V^T tile [d][j], swizzled chunks
  __shared__ unsigned short Pw[4][16 * 72];  // per-wave P^T as [i][j], stride 72
  const int lin = blockIdx.x + 32 * blockIdx.y;
  const int xcd = lin & 7, slot = lin >> 3;
  const int h = slot >> 2;
  const int qbase = (xcd * 4 + (slot & 3)) * 64;
  const int tid = threadIdx.x;
  const int lane = tid & 63, w = tid >> 6;
  const int quad = lane >> 4, l16 = lane & 15;
  const int qrow0 = qbase + w * 16;
  unsigned short* pws = &Pw[w][0];

  // Q B-fragment: lane = col i = l16, k = d = ks*32 + quad*8 + jj
  bf16x8 aq[2];
  {
    const unsigned short* qp = QKV + (size_t)(qrow0 + l16) * QKVLD + h * HD + quad * 8;
    aq[0] = *(const bf16x8*)qp;
    aq[1] = *(const bf16x8*)(qp + 32);
  }

  f32x4 accO[4] = {};
  float lsum = 0.f;

  const int jlo = (qbase >= 512) ? (qbase - 512) : 0;
  const int ng = (jlo > 0) ? ((jlo + 511) >> 9) : 0;  // global cols below window
  const int ntl = ((qbase - jlo) >> 6) + 1;           // local 64-wide tiles

  auto stage = [&](int j0, int b) {
#pragma unroll
    for (int c = tid; c < 512; c += 256) {
      int r = c >> 3, kc = c & 7;
      int g = (kc & 4) + ((kc & 3) ^ (r & 3));
      gld_lds16(QKV + (size_t)(j0 + r) * QKVLD + HID + h * HD + g * 8, &Ks[b][c * 8]);
      gld_lds16(VtG + (size_t)(h * HD + r) * SEQ + j0 + g * 8, &Vt[b][c * 8]);
    }
  };

  stage(jlo, 0);
  __syncthreads();

  for (int t = 0; t < ntl; t++) {
    if (t + 1 < ntl) stage(jlo + (t + 1) * 64, (t + 1) & 1);
    const unsigned short* KsB = Ks[t & 1];
    const unsigned short* VtB = Vt[t & 1];
    const int j0 = jlo + t * 64;

    // S^T: A = K (m=j), B = Q (n=i)
    f32x4 s[4] = {};
#pragma unroll
    for (int nj = 0; nj < 4; nj++) {
      int row = nj * 16 + l16;
#pragma unroll
      for (int ks = 0; ks < 2; ks++) {
        bf16x8 ak = *(const bf16x8*)(KsB + (row * 8 + ks * 4 + (quad ^ (row & 3))) * 8);
        s[nj] = __builtin_amdgcn_mfma_f32_16x16x32_bf16(ak, aq[ks], s[nj], 0, 0, 0);
      }
    }

    const bool isdiag = (t == ntl - 1);
    const bool istrail = (t == 0) && (qbase >= 512);
    const int trailg = (istrail && ((j0 & 511) == 0)) ? 1 : 0;
    const int db = qrow0 + l16 - j0 - quad * 4;  // i-j = db - nj*16 - r
#pragma unroll
    for (int nj = 0; nj < 4; nj++) {
      float p[4];
#pragma unroll
      for (int r = 0; r < 4; r++) {
        float x = s[nj][r];
        int d = db - nj * 16 - r;
        bool valid = true;
        if (isdiag) valid = (d >= 0);
        else if (istrail) valid = (d <= 512) || (trailg && (nj * 16 + quad * 4 + r) == 0);
        x = valid ? x : -1e30f;  // exp -> 0
        p[r] = __expf(x);
        lsum += p[r];
      }
      *(uint2*)(pws + l16 * 72 + nj * 16 + quad * 4) =
          make_uint2(pkbf(p[0], p[1]), pkbf(p[2], p[3]));
    }

    // O^T += V^T * P^T (within-wave LDS dependency; no barrier needed)
#pragma unroll
    for (int kk = 0; kk < 2; kk++) {
      bf16x8 bp = *(const bf16x8*)(pws + l16 * 72 + kk * 32 + quad * 8);
#pragma unroll
      for (int nd = 0; nd < 4; nd++) {
        int row = nd * 16 + l16;
        bf16x8 av = *(const bf16x8*)(VtB + (row * 8 + kk * 4 + (quad ^ (row & 3))) * 8);
        accO[nd] = __builtin_amdgcn_mfma_f32_16x16x32_bf16(av, bp, accO[nd], 0, 0, 0);
      }
    }
    __syncthreads();  // one barrier/tile: drains prefetch, fences both buffers
  }

  // ---- compact global tile last (order-free softmax; buffers fenced by loop) ----
  if (ng > 0) {
    if (tid < ng * 8) {  // K rows c<ng at j=512c
      int r = tid >> 3, kc = tid & 7;
      int g = (kc & 4) + ((kc & 3) ^ (r & 3));
      *(uint4*)(&Ks[0][tid * 8]) =
          *(const uint4*)(QKV + ((size_t)r << 9) * QKVLD + HID + h * HD + g * 8);
    }
    if (tid < ng * 64) {  // V^T cols c<ng (elem (d,c) lands in chunk kc=d&3, offset c)
      int d = tid & 63, c = tid >> 6;
      Vt[0][(d * 8 + (d & 3)) * 8 + c] = VtG[(size_t)(h * HD + d) * SEQ + ((size_t)c << 9)];
    }
    __syncthreads();
    f32x4 s0 = {};
#pragma unroll
    for (int ks = 0; ks < 2; ks++) {
      bf16x8 ak = *(const bf16x8*)(&Ks[0][(l16 * 8 + ks * 4 + (quad ^ (l16 & 3))) * 8]);
      s0 = __builtin_amdgcn_mfma_f32_16x16x32_bf16(ak, aq[ks], s0, 0, 0, 0);
    }
    float p[4];
#pragma unroll
    for (int r = 0; r < 4; r++) {
      p[r] = ((quad * 4 + r) < ng) ? __expf(s0[r]) : 0.f;
      lsum += p[r];
    }
    *(uint2*)(pws + l16 * 72 + quad * 4) = make_uint2(pkbf(p[0], p[1]), pkbf(p[2], p[3]));
    *(uint2*)(pws + l16 * 72 + 16 + quad * 4) = make_uint2(0, 0);  // zero j in [16,32)
    bf16x8 bp = *(const bf16x8*)(pws + l16 * 72 + quad * 8);  // kk=0 only (j<32)
#pragma unroll
    for (int nd = 0; nd < 4; nd++) {
      int row = nd * 16 + l16;
      bf16x8 av = *(const bf16x8*)(&Vt[0][(row * 8 + (quad ^ (row & 3))) * 8]);
      accO[nd] = __builtin_amdgcn_mfma_f32_16x16x32_bf16(av, bp, accO[nd], 0, 0, 0);
    }
  }

  // ---- reduce l across quads, normalize, vectorized store ----
  lsum += __shfl_xor(lsum, 16);
  lsum += __shfl_xor(lsum, 32);
  const float rl = 1.0f / lsum;
  const int i = qrow0 + l16;
#pragma unroll
  for (int nd = 0; nd < 4; nd++) {
    *(uint2*)(AttO + (size_t)i * HID + h * HD + nd * 16 + quad * 4) =
        make_uint2(pkbf(accO[nd][0] * rl, accO[nd][1] * rl),
                   pkbf(accO[nd][2] * rl, accO[nd][3] * rl));
  }
}

extern "C" void kernel_launch(void* const* d_in, const int* in_sizes, int n_in,
                              void* d_out, int out_size, void* d_ws, size_t ws_size,
                              hipStream_t stream) {
  const float* X  = (const float*)d_in[0];
  const float* Wq = (const float*)d_in[1];
  const float* Wk = (const float*)d_in[2];
  const float* Wv = (const float*)d_in[3];
  const float* Wo = (const float*)d_in[4];
  float* out = (float*)d_out;

  unsigned short* Xb    = (unsigned short*)d_ws;                  // 2048x1024
  unsigned short* WtQKV = Xb + (size_t)SEQ * HID;                 // 3072x1024
  unsigned short* WtO   = WtQKV + (size_t)QKVLD * HID;            // 1024x1024
  unsigned short* QKV   = WtO + (size_t)HID * HID;                // 2048x3072 (V block unused)
  unsigned short* VtG   = QKV + (size_t)SEQ * QKVLD;              // 1024x2048 (V transposed)
  unsigned short* AttO  = VtG + (size_t)HID * SEQ;                // 2048x1024

  prep<<<dim3(32, 32, 5), dim3(32, 8), 0, stream>>>(X, Wq, Wk, Wv, Wo, Xb, WtQKV, WtO);

  // QKV: 128x96 tiles, grid 32x16=512 (2/CU), XCD rect 8x8 (A 2MB + B 1.5MB per L2)
  gemm_bt<4, 96, 32, 8, 2><<<dim3(32, 16), dim3(256), 0, stream>>>(
      Xb, WtQKV, QKV, VtG, SEQ, QKVLD, HID);

  attn_sparse<<<dim3(SEQ / 64, NH), dim3(256), 0, stream>>>(QKV, VtG, AttO);

  // out-proj: 64x64 tiles, grid 16x32=512 (2/CU), XCD rect 4x16 (A 2MB + B 0.5MB)
  gemm_bt<2, 64, 16, 4, 0><<<dim3(16, 32), dim3(256), 0, stream>>>(
      AttO, WtO, out, nullptr, SEQ, HID, HID);
}

// Round 12
// 126.360 us; speedup vs baseline: 2.1573x; 1.0113x over previous
//
#include <hip/hip_runtime.h>
#include <hip/hip_bf16.h>

#define SEQ 2048
#define HID 1024
#define NH 16
#define HD 64
#define QKVLD 3072

typedef __attribute__((ext_vector_type(8))) short bf16x8;
typedef __attribute__((ext_vector_type(4))) float f32x4;

__device__ __forceinline__ unsigned short f2bf(float f) {
  unsigned int x = __float_as_uint(f);
  x += 0x7fffu + ((x >> 16) & 1u);
  return (unsigned short)(x >> 16);
}

// packed f32x2 -> bf16x2 (v_cvt_pk_bf16_f32, RNE - same rounding as f2bf)
__device__ __forceinline__ unsigned int pkbf(float a, float b) {
  union { __hip_bfloat162 h2; unsigned int u; } cvt;
  cvt.h2 = __float22bfloat162_rn(make_float2(a, b));
  return cvt.u;
}

__device__ __forceinline__ void gld_lds16(const void* g, void* l) {
  __builtin_amdgcn_global_load_lds((__attribute__((address_space(1))) void*)g,
                                   (__attribute__((address_space(3))) void*)l, 16, 0, 0);
}

// ---------------- prep: z<4 -> weight transpose f32->bf16^T, z==4 -> cvt X ----------------
// z=0: Wq (scaled by 0.125 = 1/sqrt(HD)), z=1: Wk, z=2: Wv, z=3: Wo
__global__ void prep(const float* __restrict__ X, const float* __restrict__ Wq,
                     const float* __restrict__ Wk, const float* __restrict__ Wv,
                     const float* __restrict__ Wo, unsigned short* __restrict__ Xb,
                     unsigned short* __restrict__ WtQKV, unsigned short* __restrict__ WtO) {
  const int z = blockIdx.z;
  if (z == 4) {  // convert X -> bf16, 1024 blocks x 2048 elems
    int bid = blockIdx.y * 32 + blockIdx.x;
    int t = threadIdx.y * 32 + threadIdx.x;
    size_t base = (size_t)bid * 2048 + t * 4;
#pragma unroll
    for (int half = 0; half < 2; half++) {
      float4 v = *(const float4*)(X + base + half * 1024);
      *(uint2*)(Xb + base + half * 1024) = make_uint2(pkbf(v.x, v.y), pkbf(v.z, v.w));
    }
    return;
  }
  __shared__ float tile[32][33];
  const float* S = (z == 0) ? Wq : (z == 1) ? Wk : (z == 2) ? Wv : Wo;
  unsigned short* D = (z < 3) ? (WtQKV + (size_t)z * HID * HID) : WtO;
  const float scale = (z == 0) ? 0.125f : 1.0f;
  int r0 = blockIdx.y * 32, c0 = blockIdx.x * 32;
  int tx = threadIdx.x, ty = threadIdx.y;
#pragma unroll
  for (int k = 0; k < 4; k++)
    tile[ty + k * 8][tx] = S[(size_t)(r0 + ty + k * 8) * HID + c0 + tx];
  __syncthreads();
#pragma unroll
  for (int k = 0; k < 4; k++)
    D[(size_t)(c0 + ty + k * 8) * HID + r0 + tx] = f2bf(scale * tile[tx][ty + k * 8]);
}

// ---------------- GEMM: C[M,N] = A[M,K](bf16) * Bt[N,K](bf16)^T ----------------
// Tile (MI*32) x BN, K-step BK. 4 waves in 2x2; wave tile (MI*16) x (BN/2).
// LDS row: BK/8 chunks of 16B; slot kc holds global chunk g=(kc&~3)|((kc&3)^(r&3))
// (XOR swizzle per 32-k half). Frag read for (ks,quad): chunk ks*4+(quad^(r&3)).
// XCD-rect swizzle: lin&7 = XCD (dispatch heuristic); each XCD gets a contiguous
// RW x (XB/RW) rectangle of its XB blocks so A/B slices fit the 4 MB per-XCD L2.
// WPE = min waves/SIMD (occupancy request; caps VGPRs accordingly).
// OUT==0: f32 row-major. OUT==2: bf16 row-major for cols<2048, transposed
// uint2 into Vout for cols>=2048 (the V block of the QKV projection).
template <int MI, int BN, int BK, int GX, int RW, int XB, int WPE, int OUT>
__global__ __launch_bounds__(256, WPE) void gemm_bt(const unsigned short* __restrict__ A,
                                                    const unsigned short* __restrict__ Bt,
                                                    void* __restrict__ Cout,
                                                    unsigned short* __restrict__ Vout,
                                                    int M, int N, int K) {
  constexpr int NI = BN / 32;   // per-wave n-frags (wave covers BN/2 cols)
  constexpr int TM = MI * 32;   // block rows
  constexpr int KC = BK / 8;    // 16B chunks per LDS row
  __shared__ unsigned short As[TM * BK];
  __shared__ unsigned short Bs[BN * BK];
  const int tid = threadIdx.x;
  const int lane = tid & 63;
  const int w = tid >> 6;
  const int wm = w >> 1, wn = w & 1;
  const int quad = lane >> 4, l16 = lane & 15;

  const int lin = blockIdx.x + GX * blockIdx.y;
  const int xcd = lin & 7, idx = lin >> 3;
  const int bx = (xcd & 3) * RW + (idx % RW);
  const int by = (xcd >> 2) * (XB / RW) + (idx / RW);
  const int bm = by * TM, bn = bx * BN;

  f32x4 acc[MI][NI] = {};

  for (int k0 = 0; k0 < K; k0 += BK) {
#pragma unroll
    for (int c = tid; c < TM * KC; c += 256) {
      int r = c / KC, kc = c % KC;
      int g = (kc & ~3) | ((kc & 3) ^ (r & 3));
      gld_lds16(A + (size_t)(bm + r) * K + k0 + g * 8, As + c * 8);
    }
#pragma unroll
    for (int c = tid; c < BN * KC; c += 256) {
      int r = c / KC, kc = c % KC;
      int g = (kc & ~3) | ((kc & 3) ^ (r & 3));
      gld_lds16(Bt + (size_t)(bn + r) * K + k0 + g * 8, Bs + c * 8);
    }
    __syncthreads();
#pragma unroll
    for (int ks = 0; ks < BK / 32; ks++) {
      bf16x8 af[MI], bfr[NI];
#pragma unroll
      for (int mi = 0; mi < MI; mi++) {
        int m = wm * (MI * 16) + mi * 16 + l16;
        af[mi] = *(const bf16x8*)(As + (m * KC + ks * 4 + (quad ^ (m & 3))) * 8);
      }
#pragma unroll
      for (int ni = 0; ni < NI; ni++) {
        int n = wn * (BN / 2) + ni * 16 + l16;
        bfr[ni] = *(const bf16x8*)(Bs + (n * KC + ks * 4 + (quad ^ (n & 3))) * 8);
      }
#pragma unroll
      for (int mi = 0; mi < MI; mi++)
#pragma unroll
        for (int ni = 0; ni < NI; ni++)
          acc[mi][ni] = __builtin_amdgcn_mfma_f32_16x16x32_bf16(af[mi], bfr[ni], acc[mi][ni], 0, 0, 0);
    }
    __syncthreads();
  }

#pragma unroll
  for (int mi = 0; mi < MI; mi++) {
#pragma unroll
    for (int ni = 0; ni < NI; ni++) {
      int row = bm + wm * (MI * 16) + mi * 16 + quad * 4;
      int col = bn + wn * (BN / 2) + ni * 16 + l16;
      if (OUT == 0) {
#pragma unroll
        for (int r = 0; r < 4; r++)
          ((float*)Cout)[(size_t)(row + r) * N + col] = acc[mi][ni][r];
      } else {
        if (col < 2 * HID) {
#pragma unroll
          for (int r = 0; r < 4; r++)
            ((unsigned short*)Cout)[(size_t)(row + r) * N + col] = f2bf(acc[mi][ni][r]);
        } else {
          *(uint2*)(Vout + (size_t)(col - 2 * HID) * SEQ + row) =
              make_uint2(pkbf(acc[mi][ni][0], acc[mi][ni][1]),
                         pkbf(acc[mi][ni][2], acc[mi][ni][3]));
        }
      }
    }
  }
}

// ---------------- sparse flash attention (S^T form, fixed-max softmax) ----------------
// grid (SEQ/64, NH) linearized; XCD-aware remap: lin%8 selects the XCD so each
// XCD gets contiguous q-block runs whose K/V slices stay L2-resident.
// Double-buffered K/V tiles: staging for tile t+1 issues before computing tile
// t; ONE barrier per tile (buffer B=(t+1)&1 was last read at t-1, whose barrier
// fences it) -> vmcnt drain overlaps a full tile of compute. LDS 41 KB, 3/CU.
// Wave w handles q rows [qbase+w*16,+16). S^T = K·Q^T so C-layout row=j, col=i:
// lsum per-lane f32 scalar, P^T packs via v_cvt_pk_bf16_f32, O^T -> uint2 store.
// Q pre-scaled by 1/sqrt(HD); no exp clamp (scores ~N(0,1), max ~5.5 sigma).
__global__ __launch_bounds__(256, 3) void attn_sparse(const unsigned short* __restrict__ QKV,
                                                      const unsigned short* __restrict__ VtG,
                                                      unsigned short* __restrict__ AttO) {
  __shared__ unsigned short Ks[2][64 * 64];  // K tile [j][d], swizzled chunks
  __shared__ unsigned short Vt[2][64 * 64];  // V^T tile [d][j], swizzled chunks
  __shared__ unsigned short Pw[4][16 * 72];  // per-wave P^T as [i][j], stride 72
  const int lin = blockIdx.x + 32 * blockIdx.y;
  const int xcd = lin & 7, slot = lin >> 3;
  const int h = slot >> 2;
  const int qbase = (xcd * 4 + (slot & 3)) * 64;
  const int tid = threadIdx.x;
  const int lane = tid & 63, w = tid >> 6;
  const int quad = lane >> 4, l16 = lane & 15;
  const int qrow0 = qbase + w * 16;
  unsigned short* pws = &Pw[w][0];

  // Q B-fragment: lane = col i = l16, k = d = ks*32 + quad*8 + jj
  bf16x8 aq[2];
  {
    const unsigned short* qp = QKV + (size_t)(qrow0 + l16) * QKVLD + h * HD + quad * 8;
    aq[0] = *(const bf16x8*)qp;
    aq[1] = *(const bf16x8*)(qp + 32);
  }

  f32x4 accO[4] = {};
  float lsum = 0.f;

  const int jlo = (qbase >= 512) ? (qbase - 512) : 0;
  const int ng = (jlo > 0) ? ((jlo + 511) >> 9) : 0;  // global cols below window
  const int ntl = ((qbase - jlo) >> 6) + 1;           // local 64-wide tiles

  auto stage = [&](int j0, int b) {
#pragma unroll
    for (int c = tid; c < 512; c += 256) {
      int r = c >> 3, kc = c & 7;
      int g = (kc & 4) + ((kc & 3) ^ (r & 3));
      gld_lds16(QKV + (size_t)(j0 + r) * QKVLD + HID + h * HD + g * 8, &Ks[b][c * 8]);
      gld_lds16(VtG + (size_t)(h * HD + r) * SEQ + j0 + g * 8, &Vt[b][c * 8]);
    }
  };

  stage(jlo, 0);
  __syncthreads();

  for (int t = 0; t < ntl; t++) {
    if (t + 1 < ntl) stage(jlo + (t + 1) * 64, (t + 1) & 1);
    const unsigned short* KsB = Ks[t & 1];
    const unsigned short* VtB = Vt[t & 1];
    const int j0 = jlo + t * 64;

    // S^T: A = K (m=j), B = Q (n=i)
    f32x4 s[4] = {};
#pragma unroll
    for (int nj = 0; nj < 4; nj++) {
      int row = nj * 16 + l16;
#pragma unroll
      for (int ks = 0; ks < 2; ks++) {
        bf16x8 ak = *(const bf16x8*)(KsB + (row * 8 + ks * 4 + (quad ^ (row & 3))) * 8);
        s[nj] = __builtin_amdgcn_mfma_f32_16x16x32_bf16(ak, aq[ks], s[nj], 0, 0, 0);
      }
    }

    const bool isdiag = (t == ntl - 1);
    const bool istrail = (t == 0) && (qbase >= 512);
    const int trailg = (istrail && ((j0 & 511) == 0)) ? 1 : 0;
    const int db = qrow0 + l16 - j0 - quad * 4;  // i-j = db - nj*16 - r
#pragma unroll
    for (int nj = 0; nj < 4; nj++) {
      float p[4];
#pragma unroll
      for (int r = 0; r < 4; r++) {
        float x = s[nj][r];
        int d = db - nj * 16 - r;
        bool valid = true;
        if (isdiag) valid = (d >= 0);
        else if (istrail) valid = (d <= 512) || (trailg && (nj * 16 + quad * 4 + r) == 0);
        x = valid ? x : -1e30f;  // exp -> 0
        p[r] = __expf(x);
        lsum += p[r];
      }
      *(uint2*)(pws + l16 * 72 + nj * 16 + quad * 4) =
          make_uint2(pkbf(p[0], p[1]), pkbf(p[2], p[3]));
    }

    // O^T += V^T * P^T (within-wave LDS dependency; no barrier needed)
#pragma unroll
    for (int kk = 0; kk < 2; kk++) {
      bf16x8 bp = *(const bf16x8*)(pws + l16 * 72 + kk * 32 + quad * 8);
#pragma unroll
      for (int nd = 0; nd < 4; nd++) {
        int row = nd * 16 + l16;
        bf16x8 av = *(const bf16x8*)(VtB + (row * 8 + kk * 4 + (quad ^ (row & 3))) * 8);
        accO[nd] = __builtin_amdgcn_mfma_f32_16x16x32_bf16(av, bp, accO[nd], 0, 0, 0);
      }
    }
    __syncthreads();  // one barrier/tile: drains prefetch, fences both buffers
  }

  // ---- compact global tile last (order-free softmax; buffers fenced by loop) ----
  if (ng > 0) {
    if (tid < ng * 8) {  // K rows c<ng at j=512c
      int r = tid >> 3, kc = tid & 7;
      int g = (kc & 4) + ((kc & 3) ^ (r & 3));
      *(uint4*)(&Ks[0][tid * 8]) =
          *(const uint4*)(QKV + ((size_t)r << 9) * QKVLD + HID + h * HD + g * 8);
    }
    if (tid < ng * 64) {  // V^T cols c<ng (elem (d,c) lands in chunk kc=d&3, offset c)
      int d = tid & 63, c = tid >> 6;
      Vt[0][(d * 8 + (d & 3)) * 8 + c] = VtG[(size_t)(h * HD + d) * SEQ + ((size_t)c << 9)];
    }
    __syncthreads();
    f32x4 s0 = {};
#pragma unroll
    for (int ks = 0; ks < 2; ks++) {
      bf16x8 ak = *(const bf16x8*)(&Ks[0][(l16 * 8 + ks * 4 + (quad ^ (l16 & 3))) * 8]);
      s0 = __builtin_amdgcn_mfma_f32_16x16x32_bf16(ak, aq[ks], s0, 0, 0, 0);
    }
    float p[4];
#pragma unroll
    for (int r = 0; r < 4; r++) {
      p[r] = ((quad * 4 + r) < ng) ? __expf(s0[r]) : 0.f;
      lsum += p[r];
    }
    *(uint2*)(pws + l16 * 72 + quad * 4) = make_uint2(pkbf(p[0], p[1]), pkbf(p[2], p[3]));
    *(uint2*)(pws + l16 * 72 + 16 + quad * 4) = make_uint2(0, 0);  // zero j in [16,32)
    bf16x8 bp = *(const bf16x8*)(pws + l16 * 72 + quad * 8);  // kk=0 only (j<32)
#pragma unroll
    for (int nd = 0; nd < 4; nd++) {
      int row = nd * 16 + l16;
      bf16x8 av = *(const bf16x8*)(&Vt[0][(row * 8 + (quad ^ (row & 3))) * 8]);
      accO[nd] = __builtin_amdgcn_mfma_f32_16x16x32_bf16(av, bp, accO[nd], 0, 0, 0);
    }
  }

  // ---- reduce l across quads, normalize, vectorized store ----
  lsum += __shfl_xor(lsum, 16);
  lsum += __shfl_xor(lsum, 32);
  const float rl = 1.0f / lsum;
  const int i = qrow0 + l16;
#pragma unroll
  for (int nd = 0; nd < 4; nd++) {
    *(uint2*)(AttO + (size_t)i * HID + h * HD + nd * 16 + quad * 4) =
        make_uint2(pkbf(accO[nd][0] * rl, accO[nd][1] * rl),
                   pkbf(accO[nd][2] * rl, accO[nd][3] * rl));
  }
}

extern "C" void kernel_launch(void* const* d_in, const int* in_sizes, int n_in,
                              void* d_out, int out_size, void* d_ws, size_t ws_size,
                              hipStream_t stream) {
  const float* X  = (const float*)d_in[0];
  const float* Wq = (const float*)d_in[1];
  const float* Wk = (const float*)d_in[2];
  const float* Wv = (const float*)d_in[3];
  const float* Wo = (const float*)d_in[4];
  float* out = (float*)d_out;

  unsigned short* Xb    = (unsigned short*)d_ws;                  // 2048x1024
  unsigned short* WtQKV = Xb + (size_t)SEQ * HID;                 // 3072x1024
  unsigned short* WtO   = WtQKV + (size_t)QKVLD * HID;            // 1024x1024
  unsigned short* QKV   = WtO + (size_t)HID * HID;                // 2048x3072 (V block unused)
  unsigned short* VtG   = QKV + (size_t)SEQ * QKVLD;              // 1024x2048 (V transposed)
  unsigned short* AttO  = VtG + (size_t)HID * SEQ;                // 2048x1024

  prep<<<dim3(32, 32, 5), dim3(32, 8), 0, stream>>>(X, Wq, Wk, Wv, Wo, Xb, WtQKV, WtO);

  // QKV: 64x96 tiles BK=64, grid 32x32=1024 -> 4 blocks/CU (20.5 KB LDS, WPE=4):
  // 2x the waves/SIMD of the 128x96 config for latency hiding.
  // XCD rect 8x16 (A 2MB + B 1.5MB per L2).
  gemm_bt<2, 96, 64, 32, 8, 128, 4, 2><<<dim3(32, 32), dim3(256), 0, stream>>>(
      Xb, WtQKV, QKV, VtG, SEQ, QKVLD, HID);

  attn_sparse<<<dim3(SEQ / 64, NH), dim3(256), 0, stream>>>(QKV, VtG, AttO);

  // out-proj: 64x64 tiles BK=128, grid 16x32=512 (2/CU), XCD rect 4x16 (A 2MB + B 0.5MB)
  gemm_bt<2, 64, 128, 16, 4, 64, 2, 0><<<dim3(16, 32), dim3(256), 0, stream>>>(
      AttO, WtO, out, nullptr, SEQ, HID, HID);
}